// Round 4
// baseline (447.799 us; speedup 1.0000x reference)
//
#include <hip/hip_runtime.h>
#include <hip/hip_fp16.h>

// Problem constants (match reference)
#define BB      2048
#define CC      1024
#define FF      128
#define NBLK    256      // == CU count: 1 block/CU (capacity allows 2/CU)
#define RPB     8        // rows per block (NBLK*RPB == BB)
#define TPB     512      // 8 waves/block
#define NITER   10
#define SUBR    32       // colsum spread: 256/32 = 8-way contention/address
#define SCALING_F (2048.0f / 100000.0f)

// Static device storage: no hipMalloc, graph-capture safe. All cross-block
// data goes through agent-scope atomics (serviced at the IF coherence point,
// bypassing the non-coherent per-XCD L2s) -> no cache fences needed anywhere.
__device__ unsigned g_bar;               // monotonic full-barrier counter
__device__ unsigned g_done[NITER];       // monotonic per-iter arrival counters
__device__ float    g_meanPart[NBLK];    // per-block D partial sums
__device__ float    g_colsum[NITER][CC * SUBR];  // [t][(c<<5)|slot]
__device__ float    g_v[NITER + 1][CC];  // v_t per iter; 0.0f = "not yet" sentinel

__device__ __forceinline__ float atomLoadF(const float* p) {
    return __hip_atomic_load(p, __ATOMIC_RELAXED, __HIP_MEMORY_SCOPE_AGENT);
}
__device__ __forceinline__ void atomStoreF(float* p, float v) {
    __hip_atomic_store(p, v, __ATOMIC_RELAXED, __HIP_MEMORY_SCOPE_AGENT);
}

// Full grid barrier (proven round-3 primitive). Used ONCE, after phase 0.
// Monotonic counter: no reset races across graph replays; launches are
// stream-serialized so each launch's window [x, x+NBLK) is contiguous.
__device__ __forceinline__ void grid_barrier(int tid) {
    __syncthreads();
    if (tid == 0) {
        unsigned c = __hip_atomic_fetch_add(&g_bar, 1u, __ATOMIC_RELAXED,
                                            __HIP_MEMORY_SCOPE_AGENT);
        unsigned target = (c / NBLK) * NBLK + NBLK;
        while ((int)(__hip_atomic_load(&g_bar, __ATOMIC_RELAXED,
                                       __HIP_MEMORY_SCOPE_AGENT) - target) < 0)
            ;
    }
    __syncthreads();
}

__global__ void __launch_bounds__(TPB)
fused_sinkhorn(const int* __restrict__ users, const int* __restrict__ items,
               const float* __restrict__ D, const float* __restrict__ caps,
               const float* __restrict__ iemb, const float* __restrict__ uemb,
               float* __restrict__ out) {
    const int bid = blockIdx.x, tid = threadIdx.x;
    const int r0 = bid * RPB;

    // LDS: 4 + 16 + 32 KB = ~52.5 KB/block
    __shared__ union { float ue[RPB][FF]; float v[CC]; } uv;  // GEMM then v
    __shared__ __half dott[RPB][CC];   // 16 KB (phase0 -> phase1 only)
    __shared__ float  Kt[RPB][CC];     // 32 KB: D staging, then K, to the end
    __shared__ float  ush[RPB];
    __shared__ float  red[TPB / 64];
    __shared__ float  s2sh;

    // ---------------- phase 0 (everything independent of grid) --------------
    // zero colsum accumulators + v sentinels (atomic stores -> visible at IF)
    for (int i = bid * TPB + tid; i < NITER * SUBR * CC; i += NBLK * TPB)
        atomStoreF(&g_colsum[0][0] + i, 0.0f);
    for (int i = bid * TPB + tid; i < (NITER + 1) * CC; i += NBLK * TPB)
        atomStoreF(&g_v[0][0] + i, 0.0f);

    // owner setup: block b owns columns [4b, 4b+4); waves 0-1 are owner waves
    float bcap = 0.0f;
    int   myc  = 0;
    if (tid < 128) {
        myc  = (bid << 2) + (tid >> 5);
        bcap = caps[myc] * SCALING_F;   // b_c, hoisted for all 10+1 uses
    }

    // stage 8 user embeddings (8 rows x 32 float4)
    if (tid < 256) {
        int r = tid >> 5, f4 = tid & 31;
        int u = users[r0 + r];
        ((float4*)uv.ue[r])[f4] = ((const float4*)(uemb + (size_t)u * FF))[f4];
    }

    // own D rows -> Kt (staging for phase1) + block partial sum for mean(D)
    const float4* Dg  = (const float4*)(D + ((size_t)r0 << 10));
    float4*       KtL = (float4*)Kt;
    float p = 0.0f;
    for (int i = tid; i < RPB * CC / 4; i += TPB) {
        float4 d = Dg[i];
        KtL[i] = d;
        p += d.x + d.y + d.z + d.w;
    }
    #pragma unroll
    for (int off = 32; off > 0; off >>= 1) p += __shfl_down(p, off, 64);
    if ((tid & 63) == 0) red[tid >> 6] = p;
    __syncthreads();                     // also publishes uv.ue for the GEMM
    if (tid == 0) {
        float s = 0.0f;
        #pragma unroll
        for (int k = 0; k < TPB / 64; ++k) s += red[k];
        atomStoreF(&g_meanPart[bid], s);
    }

    // dot GEMM: dott[r][j] = ue[r] . iemb[j]; iemb stays L2-resident
    const float4* us = (const float4*)uv.ue;
    #pragma unroll
    for (int jj = 0; jj < CC / TPB; ++jj) {
        int j = jj * TPB + tid;
        float acc[RPB] = {};
        const float4* ip = (const float4*)(iemb + (size_t)j * FF);
        for (int f4 = 0; f4 < FF / 4; ++f4) {
            float4 a = ip[f4];
            #pragma unroll
            for (int r = 0; r < RPB; ++r) {
                float4 b = us[r * (FF / 4) + f4];   // broadcast LDS read
                acc[r] += a.x * b.x + a.y * b.y + a.z * b.z + a.w * b.w;
            }
        }
        #pragma unroll
        for (int r = 0; r < RPB; ++r) dott[r][j] = __float2half(acc[r]);
    }

    grid_barrier(tid);   // colsum/g_v zeros + meanPart complete; dott done

    // ---------------- phase 1: s2, K in place in LDS ------------------------
    if (tid < 64) {
        float s = 0.0f;
        #pragma unroll
        for (int k = 0; k < NBLK / 64; ++k)
            s += atomLoadF(&g_meanPart[tid + 64 * k]);
        #pragma unroll
        for (int off = 32; off > 0; off >>= 1) s += __shfl_down(s, off, 64);
        if (tid == 0) s2sh = 5.0f * (float)(BB * CC) / s;
    }
    __syncthreads();
    const float s2 = s2sh;
    const int4* it4 = (const int4*)(items + ((size_t)r0 << 10));
    for (int i = tid; i < RPB * CC / 4; i += TPB) {
        int4   iv = it4[i];
        float4 d  = KtL[i];                 // the staged D values
        int    r  = i >> 8;                 // (i*4)>>10
        float4 kv;
        kv.x = __expf(5.0f * __half2float(dott[r][iv.x]) - s2 * d.x);
        kv.y = __expf(5.0f * __half2float(dott[r][iv.y]) - s2 * d.y);
        kv.z = __expf(5.0f * __half2float(dott[r][iv.z]) - s2 * d.z);
        kv.w = __expf(5.0f * __half2float(dott[r][iv.w]) - s2 * d.w);
        KtL[i] = kv;                        // K now lives in LDS until the end
    }

    // ---------------- Sinkhorn iterations (no full barriers) ----------------
    for (int t = 0; t < NITER; ++t) {
        // ---- vsh fill: v_0 = 1; v_t (t>0) sentinel-polled from g_v[t] ----
        if (t == 0) {
            for (int c = tid; c < CC; c += TPB) uv.v[c] = 1.0f;
        } else {
            for (int c = tid; c < CC; c += TPB) {
                float v;
                do { v = atomLoadF(&g_v[t][c]); } while (v == 0.0f);
                uv.v[c] = v;
            }
        }
        __syncthreads();

        // ---- u_r = 1/(K v)_r : one wave per row ----
        {
            int r = tid >> 6, l = tid & 63;
            const float4* kr = (const float4*)Kt[r];
            const float4* v4 = (const float4*)uv.v;
            float pp = 0.0f;
            #pragma unroll
            for (int i2 = 0; i2 < 4; ++i2) {
                float4 k = kr[l + i2 * 64], v = v4[l + i2 * 64];
                pp += k.x * v.x + k.y * v.y + k.z * v.z + k.w * v.w;
            }
            #pragma unroll
            for (int off = 32; off > 0; off >>= 1) pp += __shfl_down(pp, off, 64);
            if (l == 0) ush[r] = 1.0f / pp;
        }
        __syncthreads();

        // ---- colsum partials: atomicAdd into this block's slot ----
        {
            const int slot = bid & (SUBR - 1);
            for (int c = tid; c < CC; c += TPB) {
                float s = 0.0f;
                #pragma unroll
                for (int r = 0; r < RPB; ++r) s += Kt[r][c] * ush[r];
                atomicAdd(&g_colsum[t][(c << 5) | slot], s);
            }
        }
        __syncthreads();   // drains every wave's atomicAdd acks (vmcnt(0))

        // ---- arrival count + owner publish (waves 0-1 only) ----
        // Lane 0 of waves 0 and 1 each arrive (2*NBLK per launch-window) and
        // poll until all blocks' adds for iter t are globally visible.
        if ((tid & 63) == 0 && tid < 128) {
            unsigned c = __hip_atomic_fetch_add(&g_done[t], 1u, __ATOMIC_RELAXED,
                                                __HIP_MEMORY_SCOPE_AGENT);
            unsigned target = (c / (2 * NBLK)) * (2 * NBLK) + 2 * NBLK;
            while ((int)(__hip_atomic_load(&g_done[t], __ATOMIC_RELAXED,
                                           __HIP_MEMORY_SCOPE_AGENT) - target) < 0)
                __builtin_amdgcn_s_sleep(1);
        }
        asm volatile("" ::: "memory");   // keep partial reads below the spin
        if (tid < 128) {
            // 4 owned cols x 32 slots, contiguous 512 B
            float pp = atomLoadF(&g_colsum[t][(myc << 5) | (tid & 31)]);
            #pragma unroll
            for (int off = 16; off > 0; off >>= 1)
                pp += __shfl_down(pp, off, 32);
            if ((tid & 31) == 0)
                atomStoreF(&g_v[t + 1][myc], bcap / pp);  // v > 0 always
        }
        // waves 2-7 already raced ahead to the next fill's sentinel polls
    }

    // ---------------- final: v10 = g_v[10], P = K * u10 (x) v10 -------------
    // ush still holds u10 from iteration t=9
    for (int c = tid; c < CC; c += TPB) {
        float v;
        do { v = atomLoadF(&g_v[NITER][c]); } while (v == 0.0f);
        uv.v[c] = v;
    }
    __syncthreads();

    float4* o4 = (float4*)(out + ((size_t)r0 << 10));
    for (int i = tid; i < RPB * CC / 4; i += TPB) {
        int    r  = i >> 8;
        float4 k  = KtL[i];
        float  ur = ush[r];
        float4 v  = *(const float4*)&uv.v[(i * 4) & (CC - 1)];
        float4 pv;
        pv.x = k.x * ur * v.x;  pv.y = k.y * ur * v.y;
        pv.z = k.z * ur * v.z;  pv.w = k.w * ur * v.w;
        o4[i] = pv;
    }
}

extern "C" void kernel_launch(void* const* d_in, const int* in_sizes, int n_in,
                              void* d_out, int out_size, void* d_ws, size_t ws_size,
                              hipStream_t stream) {
    const int*   users = (const int*)d_in[0];
    const int*   items = (const int*)d_in[1];
    const float* D     = (const float*)d_in[2];
    const float* caps  = (const float*)d_in[3];
    const float* iemb  = (const float*)d_in[4];
    const float* uemb  = (const float*)d_in[5];
    float* out = (float*)d_out;

    // Plain launch (graph-capture friendly). Co-residency of all 256 blocks
    // is guaranteed by capacity arithmetic (52.5 KB LDS, 8 waves -> 2
    // blocks/CU possible), which the counter/sentinel sync requires.
    hipLaunchKernelGGL(fused_sinkhorn, dim3(NBLK), dim3(TPB), 0, stream,
                       users, items, D, caps, iemb, uemb, out);
}

// Round 5
// 190.951 us; speedup vs baseline: 2.3451x; 2.3451x over previous
//
#include <hip/hip_runtime.h>
#include <hip/hip_fp16.h>

// Problem constants (match reference)
#define BB      2048
#define CC      1024
#define FF      128
#define NBLK    256      // == CU count: 1 block/CU (capacity allows 2/CU)
#define RPB     8        // rows per block (NBLK*RPB == BB)
#define TPB     512      // 8 waves/block
#define NITER   10
#define SUBR    8        // colsum spread: [k][c] layout, wave-coalesced adds
#define SCALING_F (2048.0f / 100000.0f)

// Static device storage: no hipMalloc, graph-capture safe. All cross-block
// data goes through agent-scope atomics (serviced at the IF coherence point,
// bypassing the non-coherent per-XCD L2s) -> no cache fences needed.
__device__ unsigned g_bar;                     // monotonic barrier counter
__device__ float g_meanPart[NBLK];             // per-block D partial sums
__device__ float g_colsum[NITER * SUBR * CC];  // [t][k][c] — c contiguous!

__device__ __forceinline__ float atomLoadF(const float* p) {
    return __hip_atomic_load(p, __ATOMIC_RELAXED, __HIP_MEMORY_SCOPE_AGENT);
}
__device__ __forceinline__ void atomStoreF(float* p, float v) {
    __hip_atomic_store(p, v, __ATOMIC_RELAXED, __HIP_MEMORY_SCOPE_AGENT);
}

// Proven round-3 grid barrier (tight spin, no sleep). Monotonic counter:
// window arithmetic makes it reset-free across graph replays; all arrivals
// of barrier k strictly precede any arrival of barrier k+1 (release of k
// requires the full window), so windows never interleave.
__device__ __forceinline__ void grid_barrier(int tid) {
    __syncthreads();   // also drains each wave's outstanding atomics (vmcnt)
    if (tid == 0) {
        unsigned c = __hip_atomic_fetch_add(&g_bar, 1u, __ATOMIC_RELAXED,
                                            __HIP_MEMORY_SCOPE_AGENT);
        unsigned target = (c / NBLK) * NBLK + NBLK;
        while ((int)(__hip_atomic_load(&g_bar, __ATOMIC_RELAXED,
                                       __HIP_MEMORY_SCOPE_AGENT) - target) < 0)
            ;
    }
    __syncthreads();
}

__global__ void __launch_bounds__(TPB)
fused_sinkhorn(const int* __restrict__ users, const int* __restrict__ items,
               const float* __restrict__ D, const float* __restrict__ caps,
               const float* __restrict__ iemb, const float* __restrict__ uemb,
               float* __restrict__ out) {
    const int bid = blockIdx.x, tid = threadIdx.x;
    const int r0 = bid * RPB;

    // LDS: 4 + 16 + 32 KB = ~52.5 KB/block -> 1 block/CU
    __shared__ union { float ue[RPB][FF]; float v[CC]; } uv;  // GEMM then v
    __shared__ __half dott[RPB][CC];   // 16 KB (phase0 -> phase1 only)
    __shared__ float  Kt[RPB][CC];     // 32 KB: K, phase1 to the end
    __shared__ float  ush[RPB];
    __shared__ float  red[TPB / 64];
    __shared__ float  s2sh;

    // ---------------- phase 0 (everything independent of grid) --------------
    // Register prefetches: D rows + items rows for THIS block (4 x float4 /
    // 4 x int4 per thread) so phase 1 never waits on HBM after the barrier.
    const float4* Dg  = (const float4*)(D + ((size_t)r0 << 10));
    const int4*   it4 = (const int4*)(items + ((size_t)r0 << 10));
    float4 d_reg[4];
    int4   it_reg[4];
    #pragma unroll
    for (int k = 0; k < 4; ++k) d_reg[k]  = Dg[tid + k * TPB];
    #pragma unroll
    for (int k = 0; k < 4; ++k) it_reg[k] = it4[tid + k * TPB];

    // caps for this thread's two owned columns (used every iteration + final)
    const float cap0 = caps[tid]       * SCALING_F;
    const float cap1 = caps[tid + 512] * SCALING_F;

    // zero colsum accumulators (atomic stores -> visible at IF)
    for (int i = bid * TPB + tid; i < NITER * SUBR * CC; i += NBLK * TPB)
        atomStoreF(&g_colsum[i], 0.0f);

    // stage 8 user embeddings (8 rows x 32 float4)
    if (tid < 256) {
        int r = tid >> 5, f4 = tid & 31;
        int u = users[r0 + r];
        ((float4*)uv.ue[r])[f4] = ((const float4*)(uemb + (size_t)u * FF))[f4];
    }

    // block partial sum of D (from the register prefetch)
    float p = 0.0f;
    #pragma unroll
    for (int k = 0; k < 4; ++k) {
        float4 d = d_reg[k];
        p += d.x + d.y + d.z + d.w;
    }
    #pragma unroll
    for (int off = 32; off > 0; off >>= 1) p += __shfl_down(p, off, 64);
    if ((tid & 63) == 0) red[tid >> 6] = p;
    __syncthreads();                     // also publishes uv.ue for the GEMM
    if (tid == 0) {
        float s = 0.0f;
        #pragma unroll
        for (int k = 0; k < TPB / 64; ++k) s += red[k];
        atomStoreF(&g_meanPart[bid], s);
    }

    // dot GEMM: dott[r][j] = ue[r] . iemb[j]; iemb stays L2-resident
    const float4* us = (const float4*)uv.ue;
    #pragma unroll
    for (int jj = 0; jj < CC / TPB; ++jj) {
        int j = jj * TPB + tid;
        float acc[RPB] = {};
        const float4* ip = (const float4*)(iemb + (size_t)j * FF);
        for (int f4 = 0; f4 < FF / 4; ++f4) {
            float4 a = ip[f4];
            #pragma unroll
            for (int r = 0; r < RPB; ++r) {
                float4 b = us[r * (FF / 4) + f4];   // broadcast LDS read
                acc[r] += a.x * b.x + a.y * b.y + a.z * b.z + a.w * b.w;
            }
        }
        #pragma unroll
        for (int r = 0; r < RPB; ++r) dott[r][j] = __float2half(acc[r]);
    }

    grid_barrier(tid);   // colsum zeros + meanPart complete; dott done

    // ---------------- phase 1: s2, K built in LDS (regs -> no HBM wait) -----
    if (tid < 64) {
        float s = 0.0f;
        #pragma unroll
        for (int k = 0; k < NBLK / 64; ++k)
            s += atomLoadF(&g_meanPart[tid + 64 * k]);
        #pragma unroll
        for (int off = 32; off > 0; off >>= 1) s += __shfl_down(s, off, 64);
        if (tid == 0) s2sh = 5.0f * (float)(BB * CC) / s;
    }
    __syncthreads();
    const float s2 = s2sh;
    float4* KtL = (float4*)Kt;
    #pragma unroll
    for (int k = 0; k < 4; ++k) {
        int    i  = tid + k * TPB;
        int4   iv = it_reg[k];
        float4 d  = d_reg[k];
        int    r  = i >> 8;                 // (i*4)>>10
        float4 kv;
        kv.x = __expf(5.0f * __half2float(dott[r][iv.x]) - s2 * d.x);
        kv.y = __expf(5.0f * __half2float(dott[r][iv.y]) - s2 * d.y);
        kv.z = __expf(5.0f * __half2float(dott[r][iv.z]) - s2 * d.z);
        kv.w = __expf(5.0f * __half2float(dott[r][iv.w]) - s2 * d.w);
        KtL[i] = kv;                        // K lives in LDS until the end
    }

    // ---------------- Sinkhorn iterations -----------------------------------
    for (int t = 0; t < NITER; ++t) {
        // vsh fill: v_0 = 1; else v[c] = b_c / colsum[t-1][c].
        // Explicit temps -> compiler issues all 16 relaxed atomic loads
        // back-to-back (pipelined), then sums.
        if (t == 0) {
            uv.v[tid]       = 1.0f;
            uv.v[tid + 512] = 1.0f;
        } else {
            const float* base = g_colsum + (size_t)(t - 1) * SUBR * CC;
            float t0[SUBR], t1[SUBR];
            #pragma unroll
            for (int k = 0; k < SUBR; ++k) t0[k] = atomLoadF(&base[k * CC + tid]);
            #pragma unroll
            for (int k = 0; k < SUBR; ++k) t1[k] = atomLoadF(&base[k * CC + tid + 512]);
            float s0 = 0.0f, s1 = 0.0f;
            #pragma unroll
            for (int k = 0; k < SUBR; ++k) { s0 += t0[k]; s1 += t1[k]; }
            uv.v[tid]       = cap0 / s0;
            uv.v[tid + 512] = cap1 / s1;
        }
        __syncthreads();

        // u_r = 1/(K v)_r : one wave per row
        {
            int r = tid >> 6, l = tid & 63;
            const float4* kr = (const float4*)Kt[r];
            const float4* v4 = (const float4*)uv.v;
            float pp = 0.0f;
            #pragma unroll
            for (int i2 = 0; i2 < 4; ++i2) {
                float4 k = kr[l + i2 * 64], v = v4[l + i2 * 64];
                pp += k.x * v.x + k.y * v.y + k.z * v.z + k.w * v.w;
            }
            #pragma unroll
            for (int off = 32; off > 0; off >>= 1) pp += __shfl_down(pp, off, 64);
            if (l == 0) ush[r] = 1.0f / pp;
        }
        __syncthreads();

        // colsum[t] += K^T u : 2 wave-coalesced atomicAdds per thread
        {
            float* cb = g_colsum + ((size_t)t * SUBR + (bid & (SUBR - 1))) * CC;
            float sA = 0.0f, sB = 0.0f;
            #pragma unroll
            for (int r = 0; r < RPB; ++r) {
                sA += Kt[r][tid]       * ush[r];
                sB += Kt[r][tid + 512] * ush[r];
            }
            atomicAdd(&cb[tid],       sA);
            atomicAdd(&cb[tid + 512], sB);
        }

        grid_barrier(tid);   // drains adds (vmcnt in syncthreads) + releases
    }

    // ---------------- final: v10 from colsum[9], P = K * u10 (x) v10 --------
    // ush still holds u10 from iteration t=9
    {
        const float* base = g_colsum + (size_t)(NITER - 1) * SUBR * CC;
        float t0[SUBR], t1[SUBR];
        #pragma unroll
        for (int k = 0; k < SUBR; ++k) t0[k] = atomLoadF(&base[k * CC + tid]);
        #pragma unroll
        for (int k = 0; k < SUBR; ++k) t1[k] = atomLoadF(&base[k * CC + tid + 512]);
        float s0 = 0.0f, s1 = 0.0f;
        #pragma unroll
        for (int k = 0; k < SUBR; ++k) { s0 += t0[k]; s1 += t1[k]; }
        uv.v[tid]       = cap0 / s0;
        uv.v[tid + 512] = cap1 / s1;
    }
    __syncthreads();

    float4* o4 = (float4*)(out + ((size_t)r0 << 10));
    #pragma unroll
    for (int k = 0; k < 4; ++k) {
        int    i  = tid + k * TPB;
        int    r  = i >> 8;
        float4 kk = KtL[i];
        float  ur = ush[r];
        float4 v  = *(const float4*)&uv.v[(i * 4) & (CC - 1)];
        float4 pv;
        pv.x = kk.x * ur * v.x;  pv.y = kk.y * ur * v.y;
        pv.z = kk.z * ur * v.z;  pv.w = kk.w * ur * v.w;
        o4[i] = pv;
    }
}

extern "C" void kernel_launch(void* const* d_in, const int* in_sizes, int n_in,
                              void* d_out, int out_size, void* d_ws, size_t ws_size,
                              hipStream_t stream) {
    const int*   users = (const int*)d_in[0];
    const int*   items = (const int*)d_in[1];
    const float* D     = (const float*)d_in[2];
    const float* caps  = (const float*)d_in[3];
    const float* iemb  = (const float*)d_in[4];
    const float* uemb  = (const float*)d_in[5];
    float* out = (float*)d_out;

    // Plain launch (graph-capture friendly). Co-residency of all 256 blocks
    // is guaranteed by capacity arithmetic (52.5 KB LDS, 8 waves -> 2
    // blocks/CU possible), which the monotonic barrier requires.
    hipLaunchKernelGGL(fused_sinkhorn, dim3(NBLK), dim3(TPB), 0, stream,
                       users, items, D, caps, iemb, uemb, out);
}

// Round 6
// 182.491 us; speedup vs baseline: 2.4538x; 1.0464x over previous
//
#include <hip/hip_runtime.h>
#include <hip/hip_fp16.h>

// Problem constants (match reference)
#define BB      2048
#define CC      1024
#define FF      128
#define NBLK    256      // == CU count: 1 block/CU (capacity allows 2/CU)
#define RPB     8        // rows per block (NBLK*RPB == BB)
#define TPB     512      // 8 waves/block
#define NITER   10
#define SUBR    8        // colsum spread: [k][c] layout, wave-coalesced adds
#define SCALING_F (2048.0f / 100000.0f)

// Barrier tree geometry
#define NLEAF   8        // leaf counters per barrier slot
#define LPB     32       // blocks per leaf (NBLK/NLEAF)
#define NSLOT   (NITER + 1)   // 10 iteration barriers + 1 phase-0 barrier
#define CPAD    16       // pad counters to own 64B line

// Static device storage: no hipMalloc, graph-capture safe. All cross-block
// data goes through agent-scope atomics (serviced at the IF coherence point,
// bypassing the non-coherent per-XCD L2s) -> no cache fences needed.
// All sync counters are MONOTONIC (never reset): windows derived from a
// per-launch epoch make them race-free across graph replays.
__device__ unsigned g_epoch;                    // launches so far * NBLK
__device__ unsigned g_leaf[NSLOT * NLEAF * CPAD];
__device__ unsigned g_root[NSLOT * CPAD];
__device__ unsigned g_rel [NSLOT * CPAD];       // release flag, own line
__device__ float g_meanPart[NBLK];              // per-block D partial sums
__device__ float g_colsum[NITER * SUBR * CC];   // [t][k][c] — c contiguous!

__device__ __forceinline__ float atomLoadF(const float* p) {
    return __hip_atomic_load(p, __ATOMIC_RELAXED, __HIP_MEMORY_SCOPE_AGENT);
}
__device__ __forceinline__ void atomStoreF(float* p, float v) {
    __hip_atomic_store(p, v, __ATOMIC_RELAXED, __HIP_MEMORY_SCOPE_AGENT);
}
__device__ __forceinline__ unsigned atomAddU(unsigned* p) {
    return __hip_atomic_fetch_add(p, 1u, __ATOMIC_RELAXED,
                                  __HIP_MEMORY_SCOPE_AGENT);
}

// Tree grid barrier. Arrival RMWs spread over 8 leaf lines (32 serialized
// RMWs each, in parallel) + 8 root RMWs; release is a plain store to a
// DEDICATED line that pollers read -> poll traffic never interferes with
// arrival RMWs (the round-5 single-counter barrier mixed both on one line).
// Ordering: __syncthreads drains vmcnt (colsum adds performed at LLC) before
// tid0 arrives; leaf->root->flag are data-dependent atomics; readers' loads
// issue only after the flag compare resolves (s_waitcnt + branch).
__device__ __forceinline__ void tree_barrier(int slot, unsigned e,
                                             int bid, int tid) {
    __syncthreads();
    if (tid == 0) {
        const int leaf = bid >> 5;     // 32 consecutive bids per leaf
        unsigned rl = atomAddU(&g_leaf[(slot * NLEAF + leaf) * CPAD]);
        if (rl == e * LPB + (LPB - 1)) {           // last of this leaf
            unsigned rr = atomAddU(&g_root[slot * CPAD]);
            if (rr == e * NLEAF + (NLEAF - 1))     // last leaf overall
                __hip_atomic_store(&g_rel[slot * CPAD], e + 1u,
                                   __ATOMIC_RELAXED, __HIP_MEMORY_SCOPE_AGENT);
        }
        while ((int)(__hip_atomic_load(&g_rel[slot * CPAD], __ATOMIC_RELAXED,
                                       __HIP_MEMORY_SCOPE_AGENT) - (e + 1u)) < 0)
            ;
    }
    __syncthreads();
}

__global__ void __launch_bounds__(TPB)
fused_sinkhorn(const int* __restrict__ users, const int* __restrict__ items,
               const float* __restrict__ D, const float* __restrict__ caps,
               const float* __restrict__ iemb, const float* __restrict__ uemb,
               float* __restrict__ out) {
    const int bid = blockIdx.x, tid = threadIdx.x;
    const int r0 = bid * RPB;

    // LDS: 4 + 16 + 32 KB = ~52.5 KB/block -> 1 block/CU
    __shared__ union { float ue[RPB][FF]; float v[CC]; } uv;  // GEMM then v
    __shared__ __half dott[RPB][CC];   // 16 KB (phase0 -> phase1 only)
    __shared__ float  Kt[RPB][CC];     // 32 KB: K, phase1 to the end
    __shared__ float  ush[RPB];
    __shared__ float  red[TPB / 64];
    __shared__ float  s2sh;
    __shared__ unsigned s_epoch;

    // ---------------- phase 0 (everything independent of grid) --------------
    // launch epoch: one RMW per block; all blocks of a launch see the same
    // e = ret/NBLK because launches are stream-serialized.
    if (tid == 0) s_epoch = atomAddU(&g_epoch) >> 8;   // /NBLK

    // Register prefetches: D rows + items rows for THIS block so phase 1
    // never waits on HBM after the barrier.
    const float4* Dg  = (const float4*)(D + ((size_t)r0 << 10));
    const int4*   it4 = (const int4*)(items + ((size_t)r0 << 10));
    float4 d_reg[4];
    int4   it_reg[4];
    #pragma unroll
    for (int k = 0; k < 4; ++k) d_reg[k]  = Dg[tid + k * TPB];
    #pragma unroll
    for (int k = 0; k < 4; ++k) it_reg[k] = it4[tid + k * TPB];

    // caps for this thread's two owned columns (used every iteration + final)
    const float cap0 = caps[tid]       * SCALING_F;
    const float cap1 = caps[tid + 512] * SCALING_F;

    // zero colsum accumulators (atomic stores -> visible at IF)
    for (int i = bid * TPB + tid; i < NITER * SUBR * CC; i += NBLK * TPB)
        atomStoreF(&g_colsum[i], 0.0f);

    // stage 8 user embeddings (8 rows x 32 float4)
    if (tid < 256) {
        int r = tid >> 5, f4 = tid & 31;
        int u = users[r0 + r];
        ((float4*)uv.ue[r])[f4] = ((const float4*)(uemb + (size_t)u * FF))[f4];
    }

    // block partial sum of D (from the register prefetch)
    float p = 0.0f;
    #pragma unroll
    for (int k = 0; k < 4; ++k) {
        float4 d = d_reg[k];
        p += d.x + d.y + d.z + d.w;
    }
    #pragma unroll
    for (int off = 32; off > 0; off >>= 1) p += __shfl_down(p, off, 64);
    if ((tid & 63) == 0) red[tid >> 6] = p;
    __syncthreads();             // publishes uv.ue, red, s_epoch
    const unsigned e = s_epoch;
    if (tid == 0) {
        float s = 0.0f;
        #pragma unroll
        for (int k = 0; k < TPB / 64; ++k) s += red[k];
        atomStoreF(&g_meanPart[bid], s);
    }

    // dot GEMM: dott[r][j] = ue[r] . iemb[j]; both j-columns fused so each
    // LDS broadcast read of b feeds 2 outputs (halves GEMM LDS traffic).
    {
        const float4* us  = (const float4*)uv.ue;
        const float4* ip0 = (const float4*)(iemb + (size_t)tid * FF);
        const float4* ip1 = (const float4*)(iemb + (size_t)(tid + 512) * FF);
        float acc0[RPB] = {}, acc1[RPB] = {};
        for (int f4 = 0; f4 < FF / 4; ++f4) {
            float4 a0 = ip0[f4], a1 = ip1[f4];
            #pragma unroll
            for (int r = 0; r < RPB; ++r) {
                float4 b = us[r * (FF / 4) + f4];   // broadcast LDS read
                acc0[r] += a0.x * b.x + a0.y * b.y + a0.z * b.z + a0.w * b.w;
                acc1[r] += a1.x * b.x + a1.y * b.y + a1.z * b.z + a1.w * b.w;
            }
        }
        #pragma unroll
        for (int r = 0; r < RPB; ++r) {
            dott[r][tid]       = __float2half(acc0[r]);
            dott[r][tid + 512] = __float2half(acc1[r]);
        }
    }

    tree_barrier(NITER, e, bid, tid);  // colsum zeros + meanPart complete

    // ---------------- phase 1: s2, K built in LDS (regs -> no HBM wait) -----
    if (tid < 64) {
        float s = 0.0f;
        #pragma unroll
        for (int k = 0; k < NBLK / 64; ++k)
            s += atomLoadF(&g_meanPart[tid + 64 * k]);
        #pragma unroll
        for (int off = 32; off > 0; off >>= 1) s += __shfl_down(s, off, 64);
        if (tid == 0) s2sh = 5.0f * (float)(BB * CC) / s;
    }
    __syncthreads();
    const float s2 = s2sh;
    float4* KtL = (float4*)Kt;
    #pragma unroll
    for (int k = 0; k < 4; ++k) {
        int    i  = tid + k * TPB;
        int4   iv = it_reg[k];
        float4 d  = d_reg[k];
        int    r  = i >> 8;                 // (i*4)>>10
        float4 kv;
        kv.x = __expf(5.0f * __half2float(dott[r][iv.x]) - s2 * d.x);
        kv.y = __expf(5.0f * __half2float(dott[r][iv.y]) - s2 * d.y);
        kv.z = __expf(5.0f * __half2float(dott[r][iv.z]) - s2 * d.z);
        kv.w = __expf(5.0f * __half2float(dott[r][iv.w]) - s2 * d.w);
        KtL[i] = kv;                        // K lives in LDS until the end
    }

    // ---------------- Sinkhorn iterations -----------------------------------
    for (int t = 0; t < NITER; ++t) {
        // vsh fill: v_0 = 1; else v[c] = b_c / colsum[t-1][c]
        if (t == 0) {
            uv.v[tid]       = 1.0f;
            uv.v[tid + 512] = 1.0f;
        } else {
            const float* base = g_colsum + (size_t)(t - 1) * SUBR * CC;
            float t0[SUBR], t1[SUBR];
            #pragma unroll
            for (int k = 0; k < SUBR; ++k) t0[k] = atomLoadF(&base[k * CC + tid]);
            #pragma unroll
            for (int k = 0; k < SUBR; ++k) t1[k] = atomLoadF(&base[k * CC + tid + 512]);
            float s0 = 0.0f, s1 = 0.0f;
            #pragma unroll
            for (int k = 0; k < SUBR; ++k) { s0 += t0[k]; s1 += t1[k]; }
            uv.v[tid]       = cap0 / s0;
            uv.v[tid + 512] = cap1 / s1;
        }
        __syncthreads();

        // u_r = 1/(K v)_r : one wave per row
        {
            int r = tid >> 6, l = tid & 63;
            const float4* kr = (const float4*)Kt[r];
            const float4* v4 = (const float4*)uv.v;
            float pp = 0.0f;
            #pragma unroll
            for (int i2 = 0; i2 < 4; ++i2) {
                float4 k = kr[l + i2 * 64], v = v4[l + i2 * 64];
                pp += k.x * v.x + k.y * v.y + k.z * v.z + k.w * v.w;
            }
            #pragma unroll
            for (int off = 32; off > 0; off >>= 1) pp += __shfl_down(pp, off, 64);
            if (l == 0) ush[r] = 1.0f / pp;
        }
        __syncthreads();

        // colsum[t] += K^T u : 2 wave-coalesced atomicAdds per thread
        {
            float* cb = g_colsum + ((size_t)t * SUBR + (bid & (SUBR - 1))) * CC;
            float sA = 0.0f, sB = 0.0f;
            #pragma unroll
            for (int r = 0; r < RPB; ++r) {
                sA += Kt[r][tid]       * ush[r];
                sB += Kt[r][tid + 512] * ush[r];
            }
            atomicAdd(&cb[tid],       sA);
            atomicAdd(&cb[tid + 512], sB);
        }

        tree_barrier(t, e, bid, tid);  // all colsum[t] adds performed at LLC
    }

    // ---------------- final: v10 from colsum[9], P = K * u10 (x) v10 --------
    // ush still holds u10 from iteration t=9
    {
        const float* base = g_colsum + (size_t)(NITER - 1) * SUBR * CC;
        float t0[SUBR], t1[SUBR];
        #pragma unroll
        for (int k = 0; k < SUBR; ++k) t0[k] = atomLoadF(&base[k * CC + tid]);
        #pragma unroll
        for (int k = 0; k < SUBR; ++k) t1[k] = atomLoadF(&base[k * CC + tid + 512]);
        float s0 = 0.0f, s1 = 0.0f;
        #pragma unroll
        for (int k = 0; k < SUBR; ++k) { s0 += t0[k]; s1 += t1[k]; }
        uv.v[tid]       = cap0 / s0;
        uv.v[tid + 512] = cap1 / s1;
    }
    __syncthreads();

    float4* o4 = (float4*)(out + ((size_t)r0 << 10));
    #pragma unroll
    for (int k = 0; k < 4; ++k) {
        int    i  = tid + k * TPB;
        int    r  = i >> 8;
        float4 kk = KtL[i];
        float  ur = ush[r];
        float4 v  = *(const float4*)&uv.v[(i * 4) & (CC - 1)];
        float4 pv;
        pv.x = kk.x * ur * v.x;  pv.y = kk.y * ur * v.y;
        pv.z = kk.z * ur * v.z;  pv.w = kk.w * ur * v.w;
        o4[i] = pv;
    }
}

extern "C" void kernel_launch(void* const* d_in, const int* in_sizes, int n_in,
                              void* d_out, int out_size, void* d_ws, size_t ws_size,
                              hipStream_t stream) {
    const int*   users = (const int*)d_in[0];
    const int*   items = (const int*)d_in[1];
    const float* D     = (const float*)d_in[2];
    const float* caps  = (const float*)d_in[3];
    const float* iemb  = (const float*)d_in[4];
    const float* uemb  = (const float*)d_in[5];
    float* out = (float*)d_out;

    // Plain launch (graph-capture friendly). Co-residency of all 256 blocks
    // is guaranteed by capacity arithmetic (52.5 KB LDS, 8 waves -> 2
    // blocks/CU possible), which the monotonic tree barrier requires.
    hipLaunchKernelGGL(fused_sinkhorn, dim3(NBLK), dim3(TPB), 0, stream,
                       users, items, D, caps, iemb, uemb, out);
}